// Round 6
// baseline (256.462 us; speedup 1.0000x reference)
//
#include <hip/hip_runtime.h>
#include <hip/hip_bf16.h>

typedef __attribute__((ext_vector_type(8))) short short8;
typedef __attribute__((ext_vector_type(4))) float f32x4;

#define NDIM 1024
#define INDIM 1024
#define KEXP 8
#define BROWS 8192
#define NX (BROWS * INDIM)        // x elements        8388608
#define NW (KEXP * NDIM * INDIM)  // w elements        8388608
#define NPH (BROWS * NDIM)        // partial elems     8388608

__device__ __forceinline__ unsigned int pack2bf(float a, float b) {
    __hip_bfloat162 h = __float22bfloat162_rn(make_float2(a, b));
    union { __hip_bfloat162 h; unsigned int u; } cv;
    cv.h = h;
    return cv.u;
}

__device__ __forceinline__ float bf2f(unsigned short u) {
    return __uint_as_float(((unsigned int)u) << 16);
}

__device__ __forceinline__ void gload16(const void* src, void* ldsdst) {
    __builtin_amdgcn_global_load_lds(
        (__attribute__((address_space(1))) void*)(src),
        (__attribute__((address_space(3))) void*)(ldsdst), 16, 0, 0);
}

// ============================ path A (ws >= 50.4 MB) ============================

__global__ void convert_w(const float* __restrict__ w, unsigned short* __restrict__ Wp) {
    const long i = ((long)blockIdx.x * blockDim.x + threadIdx.x) * 8;
    if (i >= NW) return;
    const float4 a = ((const float4*)(w + i))[0];
    const float4 b = ((const float4*)(w + i))[1];
    uint4 q;
    q.x = pack2bf(a.x, a.y); q.y = pack2bf(a.z, a.w);
    q.z = pack2bf(b.x, b.y); q.w = pack2bf(b.z, b.w);
    *(uint4*)(Wp + i) = q;
}

// Fused GEMM: A = bf16(ew[row,e] * x[row,i]) staged in-register (no A' buffer).
// BM=BN=256, BK=32, 8 waves of 128x64, ring-4 LDS (128 KiB), counted vmcnt gates,
// K split in 2 expert-aligned halves -> bf16 partials.
__global__ __launch_bounds__(512, 2)
void moe_gemm_fused(const float* __restrict__ x,
                    const float* __restrict__ ew,
                    const unsigned short* __restrict__ Wp,
                    unsigned short* __restrict__ Pp) {
    __shared__ __align__(16) unsigned short lds[4][16384];   // 4 x 32 KiB ring

    const int tid = threadIdx.x;
    const int bid = blockIdx.x;
    const int comp = bid & 7;          // (nt,h) == XCD: W panel (2 MB) L2-pinned
    const int nt = comp >> 1;          // 0..3
    const int h  = comp & 1;           // K half (experts 0-3 / 4-7)
    const int mt = bid >> 3;           // 0..31
    const int mbase = mt * 256;
    const int nbase = nt * 256;

    const int w  = tid >> 6;           // wave 0..7 (2M x 4N)
    const int l  = tid & 63;
    const int lr = l & 15;
    const int lg = l >> 4;
    const int wrow = (w >> 2) * 128;
    const int wcol = (w & 3) * 64;

    // ---- A staging coords: reg-staged x(f32) -> scale -> bf16 -> swizzled ds_write
    const int arow = w * 32 + (l >> 1);          // block row this lane stages
    const int sA   = (l >> 2) & 3;               // row swizzle s(r)=(r>>1)&3 (w*32: s==0)
    const int cb0  = ((l & 1) * 2) ^ sA;         // swizzled col-block for bf16[0..7]
    const int cb1  = ((l & 1) * 2 + 1) ^ sA;     // ... for bf16[8..15]
    const float* xrow = x + (size_t)(mbase + arow) * INDIM + (l & 1) * 16;

    // per-lane routing weights for the staged row (this half's 4 experts)
    float ewr0, ewr1, ewr2, ewr3;
    {
        const float* ep = ew + (size_t)(mbase + arow) * KEXP + h * 4;
        ewr0 = ep[0]; ewr1 = ep[1]; ewr2 = ep[2]; ewr3 = ep[3];
    }

    // ---- B staging coords (global_load_lds, pre-swizzled source)
    const int lrow = l >> 2;
    const int sg = (l & 3) ^ ((l >> 3) & 3);

    // ---- fragment read offsets (ushort units), same XOR involution
    const int swz = (lr >> 1) & 3;
    int aoff[8], boff[4];
#pragma unroll
    for (int m = 0; m < 8; ++m)
        aoff[m] = (wrow + m * 16 + lr) * 32 + ((lg ^ swz) * 8);
#pragma unroll
    for (int n = 0; n < 4; ++n)
        boff[n] = 8192 + (wcol + n * 16 + lr) * 32 + ((lg ^ swz) * 8);

    auto loadX = [&](float4* xr, int t) {        // 4 global_load_dwordx4 (vm)
        const float* p = xrow + (t & 31) * 32;
        xr[0] = ((const float4*)p)[0];
        xr[1] = ((const float4*)p)[1];
        xr[2] = ((const float4*)p)[2];
        xr[3] = ((const float4*)p)[3];
    };
    auto stageB = [&](int t) {                   // 2 global_load_lds (vm)
        const int e = (h * 4096 + t * 32) >> 10;
        const int bcol = (t & 31) * 32 + sg * 8;
        const unsigned short* wb = Wp + (size_t)e * (NDIM * INDIM);
#pragma unroll
        for (int i = 0; i < 2; ++i) {
            const int c = w * 2 + i;
            gload16(wb + (size_t)(nbase + c * 16 + lrow) * INDIM + bcol,
                    &lds[t & 3][8192 + c * 512]);
        }
    };
    auto scaleWrite = [&](const float4* xr, int t) {   // scale + pack + 2 ds_write_b128
        const int ei = t >> 5;                   // 0..3 within half (uniform)
        const float es = (ei & 2) ? ((ei & 1) ? ewr3 : ewr2)
                                  : ((ei & 1) ? ewr1 : ewr0);
        uint4 q0, q1;
        q0.x = pack2bf(xr[0].x * es, xr[0].y * es);
        q0.y = pack2bf(xr[0].z * es, xr[0].w * es);
        q0.z = pack2bf(xr[1].x * es, xr[1].y * es);
        q0.w = pack2bf(xr[1].z * es, xr[1].w * es);
        q1.x = pack2bf(xr[2].x * es, xr[2].y * es);
        q1.y = pack2bf(xr[2].z * es, xr[2].w * es);
        q1.z = pack2bf(xr[3].x * es, xr[3].y * es);
        q1.w = pack2bf(xr[3].z * es, xr[3].w * es);
        unsigned short* base = &lds[t & 3][arow * 32];
        *(uint4*)(base + cb0 * 8) = q0;
        *(uint4*)(base + cb1 * 8) = q1;
    };

    f32x4 acc[8][4];
#pragma unroll
    for (int mf = 0; mf < 8; ++mf)
#pragma unroll
        for (int nf = 0; nf < 4; ++nf) acc[mf][nf] = f32x4{0.f, 0.f, 0.f, 0.f};

    float4 xr0[4], xr1[4];       // named x-tile double buffer (parity-static, rule 20)

    // prologue: x(0),B(0),x(1),B(1) in flight; write A(0) (auto vmcnt(8))
    loadX(xr0, 0); stageB(0);
    loadX(xr1, 1); stageB(1);
    scaleWrite(xr0, 0);

    // body: xrCur holds x(kt+1); xrNext (holds consumed x(kt)) receives x(kt+2)
    auto tileBody = [&](int kt, float4* xrCur, float4* xrNext) {
        // gate: stage(kt) landed + A(kt) ds_write published. Steady state leaves
        // exactly {x(kt+1):4, B(kt+1):2} = 6 in flight. NEVER vmcnt(0) mid-loop.
        asm volatile("s_waitcnt vmcnt(6) lgkmcnt(0)\n\ts_barrier" ::: "memory");

        const unsigned short* lb = &lds[kt & 3][0];
        short8 af[8], bf[4];
#pragma unroll
        for (int m = 0; m < 4; ++m) af[m] = *(const short8*)(lb + aoff[m]);
#pragma unroll
        for (int n = 0; n < 4; ++n) bf[n] = *(const short8*)(lb + boff[n]);

        if (kt + 2 < 128) { loadX(xrNext, kt + 2); stageB(kt + 2); }

        __builtin_amdgcn_s_setprio(1);
#pragma unroll
        for (int m = 0; m < 4; ++m)
#pragma unroll
            for (int n = 0; n < 4; ++n)
                acc[m][n] = __builtin_amdgcn_mfma_f32_16x16x32_bf16(af[m], bf[n], acc[m][n], 0, 0, 0);
        __builtin_amdgcn_s_setprio(0);

#pragma unroll
        for (int m = 4; m < 8; ++m) af[m] = *(const short8*)(lb + aoff[m]);

        if (kt + 1 < 128) scaleWrite(xrCur, kt + 1);   // auto vmcnt(8): prefetch stays in flight

        __builtin_amdgcn_s_setprio(1);
#pragma unroll
        for (int m = 4; m < 8; ++m)
#pragma unroll
            for (int n = 0; n < 4; ++n)
                acc[m][n] = __builtin_amdgcn_mfma_f32_16x16x32_bf16(af[m], bf[n], acc[m][n], 0, 0, 0);
        __builtin_amdgcn_s_setprio(0);
    };

#pragma unroll 1
    for (int kt = 0; kt < 128; kt += 2) {
        tileBody(kt, xr1, xr0);
        tileBody(kt + 1, xr0, xr1);
    }

    // epilogue: bf16 partial store
#pragma unroll
    for (int mf = 0; mf < 8; ++mf)
#pragma unroll
        for (int j = 0; j < 4; ++j) {
            const int grow = mbase + wrow + mf * 16 + lg * 4 + j;
            unsigned short* op = Pp + (size_t)h * NPH + (size_t)grow * NDIM + nbase + wcol;
#pragma unroll
            for (int nf = 0; nf < 4; ++nf) {
                union { __hip_bfloat16 hh; unsigned short u; } cv;
                cv.hh = __float2bfloat16(acc[mf][nf][j]);
                op[nf * 16 + lr] = cv.u;
            }
        }
}

// out = P0 + P1 + ew @ bias   (exact f32 blend of the two K-halves + bias)
__global__ void reduce_blend(const unsigned short* __restrict__ Pp,
                             const float* __restrict__ ew,
                             const float* __restrict__ bias,
                             float* __restrict__ out) {
    const long base = ((long)blockIdx.x * blockDim.x + threadIdx.x) * 8;
    if (base >= NPH) return;
    const int b = (int)(base >> 10);
    const int o = (int)(base & 1023);
    const short8 p0 = *(const short8*)(Pp + base);
    const short8 p1 = *(const short8*)(Pp + NPH + base);
    const float4 ea = *(const float4*)(ew + (size_t)b * KEXP);
    const float4 e2 = *(const float4*)(ew + (size_t)b * KEXP + 4);
    const float e[8] = {ea.x, ea.y, ea.z, ea.w, e2.x, e2.y, e2.z, e2.w};
    float r[8];
#pragma unroll
    for (int j = 0; j < 8; ++j)
        r[j] = bf2f((unsigned short)p0[j]) + bf2f((unsigned short)p1[j]);
#pragma unroll
    for (int k = 0; k < 8; ++k)
#pragma unroll
        for (int j = 0; j < 8; ++j) r[j] += e[k] * bias[k * NDIM + o + j];
    *(float4*)(out + base) = make_float4(r[0], r[1], r[2], r[3]);
    *(float4*)(out + base + 4) = make_float4(r[4], r[5], r[6], r[7]);
}

// ============ path B fallback: round-4 pipeline (ws >= 33.5 MB) ============

#define BM 256
#define BN 128
#define BK 64
#define NT 128
#define ABUF 16384
#define BBUF 8192
#define BUFU (ABUF + BBUF)

__global__ void convert_bf16(const float* __restrict__ x, const float* __restrict__ w,
                             unsigned short* __restrict__ dst) {
    const long total = (long)NX + NW;
    const long stride = (long)gridDim.x * blockDim.x * 8;
    for (long i = ((long)blockIdx.x * blockDim.x + threadIdx.x) * 8; i < total; i += stride) {
        const float* s = (i < NX) ? (x + i) : (w + (i - NX));
        float4 a = ((const float4*)s)[0];
        float4 b = ((const float4*)s)[1];
        uint4 q;
        q.x = pack2bf(a.x, a.y); q.y = pack2bf(a.z, a.w);
        q.z = pack2bf(b.x, b.y); q.w = pack2bf(b.z, b.w);
        *(uint4*)(dst + i) = q;
    }
}

__global__ __launch_bounds__(512, 2)
void moe_gemm_pipe(const unsigned short* __restrict__ ab,
                   const float* __restrict__ ew,
                   const float* __restrict__ bias,
                   float* __restrict__ out) {
    __shared__ __align__(16) unsigned short lds[3 * BUFU];

    const int tid = threadIdx.x;
    const int bid = blockIdx.x;
    const int nt = bid & 7;
    const int mt = bid >> 3;
    const int mbase = mt * BM;
    const int nbase = nt * BN;

    const int w  = tid >> 6;
    const int l  = tid & 63;
    const int lr = l & 15;
    const int lg = l >> 4;
    const int wrow = (w >> 1) * 64;
    const int wcol = (w & 1) * 64;

    const int lrow = l >> 2;
    const int sg = (l & 3) ^ ((l >> 3) & 3);

    const unsigned short* Xb = ab;
    const unsigned short* Wb = ab + NX;

    const int swz = (lr >> 1) & 3;
    int aoff[4][2], boff[4][2];
#pragma unroll
    for (int m = 0; m < 4; ++m)
#pragma unroll
        for (int ks = 0; ks < 2; ++ks)
            aoff[m][ks] = ks * 8192 + (wrow + m * 16 + lr) * 32 + ((lg ^ swz) * 8);
#pragma unroll
    for (int n = 0; n < 4; ++n)
#pragma unroll
        for (int ks = 0; ks < 2; ++ks)
            boff[n][ks] = ABUF + ks * 4096 + (wcol + n * 16 + lr) * 32 + ((lg ^ swz) * 8);

    auto stageA = [&](int buf, int kt, int i) {
        const int c = i * 8 + w;
        const int ks = c >> 4, rg = c & 15;
        const unsigned short* src = Xb + (size_t)(mbase + rg * 16 + lrow) * INDIM
                                  + (size_t)((kt & 15) * 64 + ks * 32 + sg * 8);
        gload16(src, &lds[buf * BUFU + c * 512]);
    };
    auto stageB = [&](int buf, int kt, int i) {
        const int c = i * 8 + w;
        const int ks = c >> 3, rg = c & 7;
        const unsigned short* src = Wb + (size_t)(kt >> 4) * (NDIM * INDIM)
                                  + (size_t)(nbase + rg * 16 + lrow) * INDIM
                                  + (size_t)((kt & 15) * 64 + ks * 32 + sg * 8);
        gload16(src, &lds[buf * BUFU + ABUF + c * 512]);
    };

    f32x4 acc[4][4], accT[4][4];
#pragma unroll
    for (int m = 0; m < 4; ++m)
#pragma unroll
        for (int n = 0; n < 4; ++n) {
            acc[m][n] = f32x4{0.f, 0.f, 0.f, 0.f};
            accT[m][n] = f32x4{0.f, 0.f, 0.f, 0.f};
        }

#pragma unroll
    for (int t = 0; t < 2; ++t) {
        stageA(t, t, 0); stageA(t, t, 1); stageA(t, t, 2); stageA(t, t, 3);
        stageB(t, t, 0); stageB(t, t, 1);
    }

    int bufR = 0, bufS = 2;
#pragma unroll 1
    for (int kt = 0; kt < NT; ++kt) {
        const bool doS = (kt + 2) < NT;
        const bool bnd = (kt & 15) == 15;

        if (kt < NT - 2)
            asm volatile("s_waitcnt vmcnt(6)\n\ts_barrier" ::: "memory");
        else
            asm volatile("s_waitcnt vmcnt(0)\n\ts_barrier" ::: "memory");

        float e0[4][4];
        if (bnd) {
            const int eidx = kt >> 4;
#pragma unroll
            for (int m = 0; m < 4; ++m)
#pragma unroll
                for (int j = 0; j < 4; ++j)
                    e0[m][j] = ew[(size_t)(mbase + wrow + m * 16 + lg * 4 + j) * KEXP + eidx];
        }

        const unsigned short* lb = &lds[bufR * BUFU];
        short8 a0[4], b0[4], a1[4], b1[4];
#pragma unroll
        for (int m = 0; m < 4; ++m) a0[m] = *(const short8*)(lb + aoff[m][0]);
#pragma unroll
        for (int n = 0; n < 4; ++n) b0[n] = *(const short8*)(lb + boff[n][0]);
        if (doS) {
            stageA(bufS, kt + 2, 0); stageA(bufS, kt + 2, 1);
            stageA(bufS, kt + 2, 2); stageA(bufS, kt + 2, 3);
            stageB(bufS, kt + 2, 0); stageB(bufS, kt + 2, 1);
        }
#pragma unroll
        for (int m = 0; m < 4; ++m) a1[m] = *(const short8*)(lb + aoff[m][1]);
#pragma unroll
        for (int n = 0; n < 4; ++n) b1[n] = *(const short8*)(lb + boff[n][1]);

        __builtin_amdgcn_s_setprio(1);
#pragma unroll
        for (int m = 0; m < 4; ++m)
#pragma unroll
            for (int n = 0; n < 4; ++n)
                acc[m][n] = __builtin_amdgcn_mfma_f32_16x16x32_bf16(a0[m], b0[n], acc[m][n], 0, 0, 0);
        __builtin_amdgcn_s_setprio(0);
        __builtin_amdgcn_s_setprio(1);
#pragma unroll
        for (int m = 0; m < 4; ++m)
#pragma unroll
            for (int n = 0; n < 4; ++n)
                acc[m][n] = __builtin_amdgcn_mfma_f32_16x16x32_bf16(a1[m], b1[n], acc[m][n], 0, 0, 0);
        __builtin_amdgcn_s_setprio(0);

        if (bnd) {
#pragma unroll
            for (int m = 0; m < 4; ++m)
#pragma unroll
                for (int n = 0; n < 4; ++n) {
#pragma unroll
                    for (int j = 0; j < 4; ++j)
                        accT[m][n][j] += e0[m][j] * acc[m][n][j];
                    acc[m][n] = f32x4{0.f, 0.f, 0.f, 0.f};
                }
        }

        bufR = (bufR == 2) ? 0 : bufR + 1;
        bufS = (bufS == 2) ? 0 : bufS + 1;
    }

    float bv[4][8];
#pragma unroll
    for (int n = 0; n < 4; ++n) {
        const int gc = nbase + wcol + n * 16 + lr;
#pragma unroll
        for (int kk = 0; kk < 8; ++kk) bv[n][kk] = bias[kk * NDIM + gc];
    }
#pragma unroll
    for (int m = 0; m < 4; ++m)
#pragma unroll
        for (int j = 0; j < 4; ++j) {
            const int grow = mbase + wrow + m * 16 + lg * 4 + j;
            const float4* e4 = (const float4*)(ew + (size_t)grow * KEXP);
            const float4 ea = e4[0];
            const float4 eb = e4[1];
            const float ev[8] = {ea.x, ea.y, ea.z, ea.w, eb.x, eb.y, eb.z, eb.w};
            float* op = out + (size_t)grow * NDIM + nbase + wcol;
#pragma unroll
            for (int n = 0; n < 4; ++n) {
                float t = accT[m][n][j];
#pragma unroll
                for (int kk = 0; kk < 8; ++kk) t += ev[kk] * bv[n][kk];
                op[n * 16 + lr] = t;
            }
        }
}

extern "C" void kernel_launch(void* const* d_in, const int* in_sizes, int n_in,
                              void* d_out, int out_size, void* d_ws, size_t ws_size,
                              hipStream_t stream) {
    (void)in_sizes; (void)n_in; (void)out_size;
    const float* x    = (const float*)d_in[0];
    const float* ew   = (const float*)d_in[1];
    const float* w    = (const float*)d_in[2];
    const float* bias = (const float*)d_in[3];
    float* out = (float*)d_out;

    const size_t needA = ((size_t)NW + 2 * (size_t)NPH) * sizeof(unsigned short); // 50.4 MB
    const size_t needB = (size_t)(NX + NW) * sizeof(unsigned short);              // 33.5 MB

    if (ws_size >= needA) {
        unsigned short* Wp = (unsigned short*)d_ws;
        unsigned short* Pp = Wp + NW;
        hipLaunchKernelGGL(convert_w, dim3(4096), dim3(256), 0, stream, w, Wp);
        hipLaunchKernelGGL(moe_gemm_fused, dim3(256), dim3(512), 0, stream, x, ew, Wp, Pp);
        hipLaunchKernelGGL(reduce_blend, dim3(4096), dim3(256), 0, stream, Pp, ew, bias, out);
    } else if (ws_size >= needB) {
        unsigned short* ab = (unsigned short*)d_ws;
        hipLaunchKernelGGL(convert_bf16, dim3(2048), dim3(256), 0, stream, x, w, ab);
        hipLaunchKernelGGL(moe_gemm_pipe, dim3(256), dim3(512), 0, stream, ab, ew, bias, out);
    }
}

// Round 8
// 199.388 us; speedup vs baseline: 1.2862x; 1.2862x over previous
//
#include <hip/hip_runtime.h>
#include <hip/hip_bf16.h>

typedef __attribute__((ext_vector_type(8))) short short8;
typedef __attribute__((ext_vector_type(4))) float f32x4;

#define NDIM 1024
#define INDIM 1024
#define KEXP 8
#define BROWS 8192
#define NX (BROWS * INDIM)        // x elements        8388608
#define NW (KEXP * NDIM * INDIM)  // w elements        8388608
#define NA (BROWS * KEXP * INDIM) // A' elements      67108864
#define NPH (BROWS * NDIM)        // partial elems     8388608

__device__ __forceinline__ unsigned int pack2bf(float a, float b) {
    __hip_bfloat162 h = __float22bfloat162_rn(make_float2(a, b));
    union { __hip_bfloat162 h; unsigned int u; } cv;
    cv.h = h;
    return cv.u;
}

__device__ __forceinline__ float bf2f(unsigned short u) {
    return __uint_as_float(((unsigned int)u) << 16);
}

__device__ __forceinline__ void gload16(const void* src, void* ldsdst) {
    __builtin_amdgcn_global_load_lds(
        (__attribute__((address_space(1))) void*)(src),
        (__attribute__((address_space(3))) void*)(ldsdst), 16, 0, 0);
}

// ============================ path A (ws >= 184.5 MB) ============================

// A'[b][k*1024+i] = bf16(ew[b,k] * x[b,i])   — folds routing weights into A
__global__ void convert_a(const float* __restrict__ x, const float* __restrict__ ew,
                          unsigned short* __restrict__ Ap) {
    const int t = blockIdx.x * blockDim.x + threadIdx.x;
    if (t >= (BROWS * INDIM / 8)) return;
    const int b = t >> 7;
    const int i0 = (t & 127) * 8;
    const float4 xa = *(const float4*)(x + (size_t)b * INDIM + i0);
    const float4 xb = *(const float4*)(x + (size_t)b * INDIM + i0 + 4);
    const float4 ea = *(const float4*)(ew + (size_t)b * KEXP);
    const float4 e2 = *(const float4*)(ew + (size_t)b * KEXP + 4);
    const float e[8] = {ea.x, ea.y, ea.z, ea.w, e2.x, e2.y, e2.z, e2.w};
    unsigned short* dst = Ap + (size_t)b * (KEXP * INDIM) + i0;
#pragma unroll
    for (int k = 0; k < 8; ++k) {
        const float s = e[k];
        uint4 q;
        q.x = pack2bf(xa.x * s, xa.y * s);
        q.y = pack2bf(xa.z * s, xa.w * s);
        q.z = pack2bf(xb.x * s, xb.y * s);
        q.w = pack2bf(xb.z * s, xb.w * s);
        *(uint4*)(dst + (size_t)k * INDIM) = q;
    }
}

__global__ void convert_w(const float* __restrict__ w, unsigned short* __restrict__ Wp) {
    const long i = ((long)blockIdx.x * blockDim.x + threadIdx.x) * 8;
    if (i >= NW) return;
    const float4 a = ((const float4*)(w + i))[0];
    const float4 b = ((const float4*)(w + i))[1];
    uint4 q;
    q.x = pack2bf(a.x, a.y); q.y = pack2bf(a.z, a.w);
    q.z = pack2bf(b.x, b.y); q.w = pack2bf(b.z, b.w);
    *(uint4*)(Wp + i) = q;
}

// pure bf16 GEMM, K split in 2 expert-aligned halves. BM=BN=256, BK=32,
// 8 waves of 128x64, ring-4 LDS (128 KiB), stage distance 2,
// counted gate vmcnt(4) in steady state; vmcnt(0) only for the final 2 tiles
// (whose staging has no younger ops behind it — the r7 race).
__global__ __launch_bounds__(512, 2)
void moe_gemm_ks2(const unsigned short* __restrict__ Ap,   // [8192][8192]
                  const unsigned short* __restrict__ Wp,   // [8][1024][1024]
                  unsigned short* __restrict__ Pp) {       // [2][8192][1024] partials
    __shared__ __align__(16) unsigned short lds[4][16384];   // 4 x 32 KiB ring

    const int tid = threadIdx.x;
    const int bid = blockIdx.x;
    const int comp = bid & 7;          // (nt,h) == XCD: W panel (2 MB) L2-pinned
    const int nt = comp >> 1;          // 0..3
    const int h  = comp & 1;           // K half (experts 0-3 / 4-7)
    const int mt = bid >> 3;           // 0..31
    const int mbase = mt * 256;
    const int nbase = nt * 256;
    const int kofs = h * 4096;

    const int w  = tid >> 6;           // wave 0..7 (2M x 4N)
    const int l  = tid & 63;
    const int lr = l & 15;
    const int lg = l >> 4;
    const int wrow = (w >> 2) * 128;
    const int wcol = (w & 3) * 64;

    // staging lane coords: chunk = 16 rows x 32 cols bf16 = 1024 B
    const int lrow = l >> 2;
    const int sg = (l & 3) ^ ((l >> 3) & 3);     // pre-swizzled col block (involution)
    const int swz = (lr >> 1) & 3;

    // fragment read offsets (ushort units), matching XOR involution
    int aoff[8], boff[4];
#pragma unroll
    for (int mf = 0; mf < 8; ++mf)
        aoff[mf] = (wrow + mf * 16 + lr) * 32 + ((lg ^ swz) * 8);
#pragma unroll
    for (int nf = 0; nf < 4; ++nf)
        boff[nf] = 8192 + (wcol + nf * 16 + lr) * 32 + ((lg ^ swz) * 8);

    // staging: 32 chunks/tile (A ids 0-15, B ids 16-31), wave w owns ids w*4..w*4+3
    auto stage = [&](int kt) {
        unsigned short* sl = &lds[kt & 3][0];
#pragma unroll
        for (int i = 0; i < 4; ++i) {
            const int id = w * 4 + i;
            if (id < 16) {
                // A chunk: rows mbase + id*16 .. +15, cols kofs + kt*32 + sg*8
                gload16(Ap + (size_t)(mbase + id * 16 + lrow) * (KEXP * INDIM)
                           + (size_t)(kofs + kt * 32 + sg * 8),
                        sl + id * 512);
            } else {
                const int sub = id - 16;
                const int e = h * 4 + (kt >> 5);
                const int bcol = (kt & 31) * 32 + sg * 8;
                gload16(Wp + (size_t)e * (NDIM * INDIM)
                           + (size_t)(nbase + sub * 16 + lrow) * INDIM + bcol,
                        sl + 8192 + sub * 512);
            }
        }
    };

    f32x4 acc[8][4];
#pragma unroll
    for (int mf = 0; mf < 8; ++mf)
#pragma unroll
        for (int nf = 0; nf < 4; ++nf) acc[mf][nf] = f32x4{0.f, 0.f, 0.f, 0.f};

    // prologue: tiles 0 and 1 in flight (4 + 4 vmem ops per wave, in order)
    stage(0);
    stage(1);

#pragma unroll 1
    for (int kt = 0; kt < 128; ++kt) {
        // gate: own stage(kt) landed (vmcnt<=4 leaves stage(kt+1)'s 4 ops in
        // flight), then barrier publishes all waves' staging. Final 2 tiles
        // have no ops behind their staging -> must drain fully (r7 bug-fix).
        if (kt < 126)
            asm volatile("s_waitcnt vmcnt(4)\n\ts_barrier" ::: "memory");
        else
            asm volatile("s_waitcnt vmcnt(0)\n\ts_barrier" ::: "memory");

        const unsigned short* lb = &lds[kt & 3][0];
        short8 af[8], bf[4];

        // cluster-0 operands first (compiler will wait lgkmcnt(4) before MFMA,
        // leaving af[4..7] draining under cluster-0 MFMA)
#pragma unroll
        for (int m = 0; m < 4; ++m) af[m] = *(const short8*)(lb + aoff[m]);
#pragma unroll
        for (int n = 0; n < 4; ++n) bf[n] = *(const short8*)(lb + boff[n]);

        if (kt + 2 < 128) stage(kt + 2);         // 4 vmem, 2 tiles ahead

#pragma unroll
        for (int m = 4; m < 8; ++m) af[m] = *(const short8*)(lb + aoff[m]);

        __builtin_amdgcn_s_setprio(1);
#pragma unroll
        for (int m = 0; m < 4; ++m)
#pragma unroll
            for (int n = 0; n < 4; ++n)
                acc[m][n] = __builtin_amdgcn_mfma_f32_16x16x32_bf16(af[m], bf[n], acc[m][n], 0, 0, 0);
        __builtin_amdgcn_s_setprio(0);

        __builtin_amdgcn_s_setprio(1);
#pragma unroll
        for (int m = 4; m < 8; ++m)
#pragma unroll
            for (int n = 0; n < 4; ++n)
                acc[m][n] = __builtin_amdgcn_mfma_f32_16x16x32_bf16(af[m], bf[n], acc[m][n], 0, 0, 0);
        __builtin_amdgcn_s_setprio(0);
    }

    // epilogue: bf16 partial store
#pragma unroll
    for (int mf = 0; mf < 8; ++mf)
#pragma unroll
        for (int j = 0; j < 4; ++j) {
            const int grow = mbase + wrow + mf * 16 + lg * 4 + j;
            unsigned short* op = Pp + (size_t)h * NPH + (size_t)grow * NDIM + nbase + wcol;
#pragma unroll
            for (int nf = 0; nf < 4; ++nf) {
                union { __hip_bfloat16 hh; unsigned short u; } cv;
                cv.hh = __float2bfloat16(acc[mf][nf][j]);
                op[nf * 16 + lr] = cv.u;
            }
        }
}

// out = P0 + P1 + ew @ bias   (exact f32 blend of the two K-halves + bias)
__global__ void reduce_blend(const unsigned short* __restrict__ Pp,
                             const float* __restrict__ ew,
                             const float* __restrict__ bias,
                             float* __restrict__ out) {
    const long base = ((long)blockIdx.x * blockDim.x + threadIdx.x) * 8;
    if (base >= NPH) return;
    const int b = (int)(base >> 10);
    const int o = (int)(base & 1023);
    const short8 p0 = *(const short8*)(Pp + base);
    const short8 p1 = *(const short8*)(Pp + NPH + base);
    const float4 ea = *(const float4*)(ew + (size_t)b * KEXP);
    const float4 e2 = *(const float4*)(ew + (size_t)b * KEXP + 4);
    const float e[8] = {ea.x, ea.y, ea.z, ea.w, e2.x, e2.y, e2.z, e2.w};
    float r[8];
#pragma unroll
    for (int j = 0; j < 8; ++j)
        r[j] = bf2f((unsigned short)p0[j]) + bf2f((unsigned short)p1[j]);
#pragma unroll
    for (int k = 0; k < 8; ++k)
#pragma unroll
        for (int j = 0; j < 8; ++j) r[j] += e[k] * bias[k * NDIM + o + j];
    *(float4*)(out + base) = make_float4(r[0], r[1], r[2], r[3]);
    *(float4*)(out + base + 4) = make_float4(r[4], r[5], r[6], r[7]);
}

// ============ path B fallback: round-4 pipeline (ws >= 33.5 MB) ============

#define BM 256
#define BN 128
#define BK 64
#define NT 128
#define ABUF 16384
#define BBUF 8192
#define BUFU (ABUF + BBUF)

__global__ void convert_bf16(const float* __restrict__ x, const float* __restrict__ w,
                             unsigned short* __restrict__ dst) {
    const long total = (long)NX + NW;
    const long stride = (long)gridDim.x * blockDim.x * 8;
    for (long i = ((long)blockIdx.x * blockDim.x + threadIdx.x) * 8; i < total; i += stride) {
        const float* s = (i < NX) ? (x + i) : (w + (i - NX));
        float4 a = ((const float4*)s)[0];
        float4 b = ((const float4*)s)[1];
        uint4 q;
        q.x = pack2bf(a.x, a.y); q.y = pack2bf(a.z, a.w);
        q.z = pack2bf(b.x, b.y); q.w = pack2bf(b.z, b.w);
        *(uint4*)(dst + i) = q;
    }
}

__global__ __launch_bounds__(512, 2)
void moe_gemm_pipe(const unsigned short* __restrict__ ab,
                   const float* __restrict__ ew,
                   const float* __restrict__ bias,
                   float* __restrict__ out) {
    __shared__ __align__(16) unsigned short lds[3 * BUFU];

    const int tid = threadIdx.x;
    const int bid = blockIdx.x;
    const int nt = bid & 7;
    const int mt = bid >> 3;
    const int mbase = mt * BM;
    const int nbase = nt * BN;

    const int w  = tid >> 6;
    const int l  = tid & 63;
    const int lr = l & 15;
    const int lg = l >> 4;
    const int wrow = (w >> 1) * 64;
    const int wcol = (w & 1) * 64;

    const int lrow = l >> 2;
    const int sg = (l & 3) ^ ((l >> 3) & 3);

    const unsigned short* Xb = ab;
    const unsigned short* Wb = ab + NX;

    const int swz = (lr >> 1) & 3;
    int aoff[4][2], boff[4][2];
#pragma unroll
    for (int m = 0; m < 4; ++m)
#pragma unroll
        for (int ks = 0; ks < 2; ++ks)
            aoff[m][ks] = ks * 8192 + (wrow + m * 16 + lr) * 32 + ((lg ^ swz) * 8);
#pragma unroll
    for (int n = 0; n < 4; ++n)
#pragma unroll
        for (int ks = 0; ks < 2; ++ks)
            boff[n][ks] = ABUF + ks * 4096 + (wcol + n * 16 + lr) * 32 + ((lg ^ swz) * 8);

    auto stageA = [&](int buf, int kt, int i) {
        const int c = i * 8 + w;
        const int ks = c >> 4, rg = c & 15;
        const unsigned short* src = Xb + (size_t)(mbase + rg * 16 + lrow) * INDIM
                                  + (size_t)((kt & 15) * 64 + ks * 32 + sg * 8);
        gload16(src, &lds[buf * BUFU + c * 512]);
    };
    auto stageB = [&](int buf, int kt, int i) {
        const int c = i * 8 + w;
        const int ks = c >> 3, rg = c & 7;
        const unsigned short* src = Wb + (size_t)(kt >> 4) * (NDIM * INDIM)
                                  + (size_t)(nbase + rg * 16 + lrow) * INDIM
                                  + (size_t)((kt & 15) * 64 + ks * 32 + sg * 8);
        gload16(src, &lds[buf * BUFU + ABUF + c * 512]);
    };

    f32x4 acc[4][4], accT[4][4];
#pragma unroll
    for (int m = 0; m < 4; ++m)
#pragma unroll
        for (int n = 0; n < 4; ++n) {
            acc[m][n] = f32x4{0.f, 0.f, 0.f, 0.f};
            accT[m][n] = f32x4{0.f, 0.f, 0.f, 0.f};
        }

#pragma unroll
    for (int t = 0; t < 2; ++t) {
        stageA(t, t, 0); stageA(t, t, 1); stageA(t, t, 2); stageA(t, t, 3);
        stageB(t, t, 0); stageB(t, t, 1);
    }

    int bufR = 0, bufS = 2;
#pragma unroll 1
    for (int kt = 0; kt < NT; ++kt) {
        const bool doS = (kt + 2) < NT;
        const bool bnd = (kt & 15) == 15;

        if (kt < NT - 2)
            asm volatile("s_waitcnt vmcnt(6)\n\ts_barrier" ::: "memory");
        else
            asm volatile("s_waitcnt vmcnt(0)\n\ts_barrier" ::: "memory");

        float e0[4][4];
        if (bnd) {
            const int eidx = kt >> 4;
#pragma unroll
            for (int m = 0; m < 4; ++m)
#pragma unroll
                for (int j = 0; j < 4; ++j)
                    e0[m][j] = ew[(size_t)(mbase + wrow + m * 16 + lg * 4 + j) * KEXP + eidx];
        }

        const unsigned short* lb = &lds[bufR * BUFU];
        short8 a0[4], b0[4], a1[4], b1[4];
#pragma unroll
        for (int m = 0; m < 4; ++m) a0[m] = *(const short8*)(lb + aoff[m][0]);
#pragma unroll
        for (int n = 0; n < 4; ++n) b0[n] = *(const short8*)(lb + boff[n][0]);
        if (doS) {
            stageA(bufS, kt + 2, 0); stageA(bufS, kt + 2, 1);
            stageA(bufS, kt + 2, 2); stageA(bufS, kt + 2, 3);
            stageB(bufS, kt + 2, 0); stageB(bufS, kt + 2, 1);
        }
#pragma unroll
        for (int m = 0; m < 4; ++m) a1[m] = *(const short8*)(lb + aoff[m][1]);
#pragma unroll
        for (int n = 0; n < 4; ++n) b1[n] = *(const short8*)(lb + boff[n][1]);

        __builtin_amdgcn_s_setprio(1);
#pragma unroll
        for (int m = 0; m < 4; ++m)
#pragma unroll
            for (int n = 0; n < 4; ++n)
                acc[m][n] = __builtin_amdgcn_mfma_f32_16x16x32_bf16(a0[m], b0[n], acc[m][n], 0, 0, 0);
        __builtin_amdgcn_s_setprio(0);
        __builtin_amdgcn_s_setprio(1);
#pragma unroll
        for (int m = 0; m < 4; ++m)
#pragma unroll
            for (int n = 0; n < 4; ++n)
                acc[m][n] = __builtin_amdgcn_mfma_f32_16x16x32_bf16(a1[m], b1[n], acc[m][n], 0, 0, 0);
        __builtin_amdgcn_s_setprio(0);

        if (bnd) {
#pragma unroll
            for (int m = 0; m < 4; ++m)
#pragma unroll
                for (int n = 0; n < 4; ++n) {
#pragma unroll
                    for (int j = 0; j < 4; ++j)
                        accT[m][n][j] += e0[m][j] * acc[m][n][j];
                    acc[m][n] = f32x4{0.f, 0.f, 0.f, 0.f};
                }
        }

        bufR = (bufR == 2) ? 0 : bufR + 1;
        bufS = (bufS == 2) ? 0 : bufS + 1;
    }

    float bv[4][8];
#pragma unroll
    for (int n = 0; n < 4; ++n) {
        const int gc = nbase + wcol + n * 16 + lr;
#pragma unroll
        for (int kk = 0; kk < 8; ++kk) bv[n][kk] = bias[kk * NDIM + gc];
    }
#pragma unroll
    for (int m = 0; m < 4; ++m)
#pragma unroll
        for (int j = 0; j < 4; ++j) {
            const int grow = mbase + wrow + m * 16 + lg * 4 + j;
            const float4* e4 = (const float4*)(ew + (size_t)grow * KEXP);
            const float4 ea = e4[0];
            const float4 eb = e4[1];
            const float ev[8] = {ea.x, ea.y, ea.z, ea.w, eb.x, eb.y, eb.z, eb.w};
            float* op = out + (size_t)grow * NDIM + nbase + wcol;
#pragma unroll
            for (int n = 0; n < 4; ++n) {
                float t = accT[m][n][j];
#pragma unroll
                for (int kk = 0; kk < 8; ++kk) t += ev[kk] * bv[n][kk];
                op[n * 16 + lr] = t;
            }
        }
}

extern "C" void kernel_launch(void* const* d_in, const int* in_sizes, int n_in,
                              void* d_out, int out_size, void* d_ws, size_t ws_size,
                              hipStream_t stream) {
    (void)in_sizes; (void)n_in; (void)out_size;
    const float* x    = (const float*)d_in[0];
    const float* ew   = (const float*)d_in[1];
    const float* w    = (const float*)d_in[2];
    const float* bias = (const float*)d_in[3];
    float* out = (float*)d_out;

    const size_t needA = ((size_t)NA + NW + 2 * (size_t)NPH) * sizeof(unsigned short); // 184.5 MB
    const size_t needB = (size_t)(NX + NW) * sizeof(unsigned short);                   // 33.5 MB

    if (ws_size >= needA) {
        unsigned short* Ap = (unsigned short*)d_ws;
        unsigned short* Wp = Ap + NA;
        unsigned short* Pp = Wp + NW;
        hipLaunchKernelGGL(convert_a, dim3(4096), dim3(256), 0, stream, x, ew, Ap);
        hipLaunchKernelGGL(convert_w, dim3(4096), dim3(256), 0, stream, w, Wp);
        hipLaunchKernelGGL(moe_gemm_ks2, dim3(256), dim3(512), 0, stream, Ap, Wp, Pp);
        hipLaunchKernelGGL(reduce_blend, dim3(4096), dim3(256), 0, stream, Pp, ew, bias, out);
    } else if (ws_size >= needB) {
        unsigned short* ab = (unsigned short*)d_ws;
        hipLaunchKernelGGL(convert_bf16, dim3(2048), dim3(256), 0, stream, x, w, ab);
        hipLaunchKernelGGL(moe_gemm_pipe, dim3(256), dim3(512), 0, stream, ab, ew, bias, out);
    }
}